// Round 8
// baseline (250.870 us; speedup 1.0000x reference)
//
#include <hip/hip_runtime.h>
#include <hip/hip_bf16.h>

#define L_ 64
#define B_ 32
#define S_ 64
#define D_ 512
#define V_ 32000
#define NL_ 2

typedef __attribute__((ext_vector_type(8))) short bf16x8;
typedef __attribute__((ext_vector_type(4))) float f32x4;

static __device__ __forceinline__ short f2bf(float f) {
  union { float f; unsigned u; } x; x.f = f;
  unsigned r = (x.u + 0x7FFFu + ((x.u >> 16) & 1u)) >> 16;
  return (short)r;
}

#define GLOAD_LDS16(g, l)                                                     \
  __builtin_amdgcn_global_load_lds(                                           \
      (const __attribute__((address_space(1))) void*)(g),                     \
      (__attribute__((address_space(3))) void*)(l), 16, 0, 0)

// ===== fused prep: all weight transposes (f32 [K,N] -> bf16 [N,K]) + embed ==
__global__ void prep_kernel(const float* __restrict__ sruW, const float* __restrict__ attnW,
                            const float* __restrict__ outW, const int* __restrict__ tok,
                            const float* __restrict__ tab,
                            short* __restrict__ WTs, short* __restrict__ WTa,
                            short* __restrict__ WTo,
                            float* __restrict__ xf, short* __restrict__ xb) {
  int bid = blockIdx.x;
  int tx = threadIdx.x, ty = threadIdx.y;  // (32,8)
  __shared__ float tile[32][33];
  if (bid < 18048) {
    const float* in;
    short* out;
    int K, N, bx, by;
    if (bid < 1536) {
      int l = (bid >= 768) ? 1 : 0;
      int r = bid - l * 768;
      bx = r % 48; by = r / 48; K = 512; N = 1536;
      in = sruW + (size_t)l * 512 * 1536;
      out = WTs + (size_t)l * 1536 * 512;
    } else if (bid < 2048) {
      int r = bid - 1536;
      bx = r % 16; by = r / 16; K = 1024; N = 512;
      in = attnW; out = WTa;
    } else {
      int r = bid - 2048;
      bx = r % 1000; by = r / 1000; K = 512; N = 32000;
      in = outW; out = WTo;
    }
    int x = bx * 32 + tx;
    int y0 = by * 32;
    for (int j = ty; j < 32; j += 8) {
      int y = y0 + j;
      tile[j][tx] = (x < N && y < K) ? in[(size_t)y * N + x] : 0.f;
    }
    __syncthreads();
    int xo = y0 + tx;
    int yo0 = bx * 32;
    for (int j = ty; j < 32; j += 8) {
      int yo = yo0 + j;
      if (yo < N && xo < K) out[(size_t)yo * K + xo] = f2bf(tile[tx][j]);
    }
  } else {
    int i = (bid - 18048) * 256 + ty * 32 + tx;
    int d = i & (D_ - 1);
    int lb = i >> 9;
    float v = tab[(size_t)tok[lb] * D_ + d];
    xf[i] = v;
    xb[i] = f2bf(v);
  }
}

// ===== tile-templated 2-phase bf16 MFMA GEMM (small GEMMs; proven) ==========
// MODE 0: f32 C | MODE 1: bf16 tanh(C) | MODE 3: f32, cols>=512 get
// sigmoid(v + bias[c-512]) (SRU gate fusion; bias = srub layer slice)
template <int BMt, int BNt, int WM, int WN, int MODE>
__global__ __launch_bounds__(256) void gemm_t(
    const short* __restrict__ A, const short* __restrict__ BT,
    void* __restrict__ Cptr, const float* __restrict__ bias,
    int M, int N, int K, int nbm) {
  constexpr int MI = BMt / WM / 16;
  constexpr int NI = BNt / WN / 16;
  constexpr int ACH = BMt / 8;
  constexpr int NCH = (BMt + BNt) / 8;
  constexpr int CPW = NCH / 4;

  const int nwg = gridDim.x;
  const int qc = nwg >> 3;
  const int bid = blockIdx.x;
  const int wg = (bid & 7) * qc + (bid >> 3);
  const int bm = wg % nbm;
  const int bn = wg / nbm;

  __shared__ __align__(16) short la[2][BMt * 64];
  __shared__ __align__(16) short lb[2][BNt * 64];
  const int tid = threadIdx.x;
  const int wave = tid >> 6, lane = tid & 63;
  const int wm = (wave / WN) * (BMt / WM);
  const int wn = (wave % WN) * (BNt / WN);

  f32x4 acc[MI][NI] = {};

  const int lrow = lane >> 3;
  const int lslot = lane & 7;
  const short* Abase = A + (size_t)(bm * BMt) * K;
  const short* Bbase = BT + (size_t)(bn * BNt) * K;

  auto stage = [&](int buf, int k0) {
#pragma unroll
    for (int c = 0; c < CPW; ++c) {
      int chunk = wave * CPW + c;
      if (chunk < ACH) {
        int row = chunk * 8 + lrow;
        int slot = lslot ^ (row & 7);
        GLOAD_LDS16(Abase + (size_t)row * K + k0 + slot * 8, &la[buf][chunk * 512]);
      } else {
        int bc = chunk - ACH;
        int row = bc * 8 + lrow;
        int slot = lslot ^ (row & 7);
        GLOAD_LDS16(Bbase + (size_t)row * K + k0 + slot * 8, &lb[buf][bc * 512]);
      }
    }
  };

  stage(0, 0);
  __syncthreads();

  const int nt = K / 64;
  int cur = 0;
  for (int t = 0; t < nt; ++t) {
    if (t + 1 < nt) stage(cur ^ 1, (t + 1) * 64);
#pragma unroll
    for (int kk = 0; kk < 2; ++kk) {
      bf16x8 af[MI], bfr[NI];
#pragma unroll
      for (int mi = 0; mi < MI; ++mi) {
        int row = wm + mi * 16 + (lane & 15);
        int slot = (kk * 4 + (lane >> 4)) ^ (row & 7);
        af[mi] = *(const bf16x8*)&la[cur][row * 64 + slot * 8];
      }
#pragma unroll
      for (int ni = 0; ni < NI; ++ni) {
        int row = wn + ni * 16 + (lane & 15);
        int slot = (kk * 4 + (lane >> 4)) ^ (row & 7);
        bfr[ni] = *(const bf16x8*)&lb[cur][row * 64 + slot * 8];
      }
#pragma unroll
      for (int mi = 0; mi < MI; ++mi)
#pragma unroll
        for (int ni = 0; ni < NI; ++ni)
          acc[mi][ni] = __builtin_amdgcn_mfma_f32_16x16x32_bf16(
              af[mi], bfr[ni], acc[mi][ni], 0, 0, 0);
    }
    __syncthreads();
    cur ^= 1;
  }

  const int cl = lane & 15;
  const int rl = (lane >> 4) * 4;
#pragma unroll
  for (int mi = 0; mi < MI; ++mi) {
#pragma unroll
    for (int ni = 0; ni < NI; ++ni) {
      int c = bn * BNt + wn + ni * 16 + cl;
      int r0 = bm * BMt + wm + mi * 16 + rl;
#pragma unroll
      for (int j = 0; j < 4; ++j) {
        int r = r0 + j;
        float v = acc[mi][ni][j];
        if (MODE == 0) {
          ((float*)Cptr)[(size_t)r * N + c] = v;
        } else if (MODE == 1) {
          ((short*)Cptr)[(size_t)r * N + c] = f2bf(tanhf(v));
        } else if (MODE == 3) {
          if (c >= 512) v = 1.f / (1.f + expf(-(v + bias[c - 512])));
          ((float*)Cptr)[(size_t)r * N + c] = v;
        }
      }
    }
  }
}

// ===== m97-structure single-buffer GEMM (the big V GEMM) ====================
// 32 KB LDS, VGPR~88 -> launch_bounds(256,4) gives 4 blocks/CU (16 waves).
// MODE 2: f32 C[row-remap (l*B+b)->(b*L+l)][N] + bias[n]
template <int MODE>
__global__ __launch_bounds__(256, 4) void gemm_s(
    const short* __restrict__ A, const short* __restrict__ BT,
    void* __restrict__ Cptr, const float* __restrict__ bias,
    int M, int N, int K, int nbm) {
  const int nwg = gridDim.x;
  const int qc = nwg >> 3;
  const int bid = blockIdx.x;
  const int wg = (bid & 7) * qc + (bid >> 3);
  const int bm = wg % nbm;
  const int bn = wg / nbm;

  __shared__ __align__(16) short la[128 * 64];
  __shared__ __align__(16) short lb[128 * 64];
  const int tid = threadIdx.x;
  const int wave = tid >> 6, lane = tid & 63;
  const int wm = (wave >> 1) * 64, wn = (wave & 1) * 64;

  f32x4 acc[4][4] = {};

  const int lrow = lane >> 3;
  const int lslot = lane & 7;
  const short* Abase = A + (size_t)(bm * 128) * K;
  const short* Bbase = BT + (size_t)(bn * 128) * K;

  const int nt = K / 64;
  for (int t = 0; t < nt; ++t) {
    const int k0 = t * 64;
#pragma unroll
    for (int c = 0; c < 4; ++c) {
      int chunk = wave * 4 + c;
      int row = chunk * 8 + lrow;
      int slot = lslot ^ (row & 7);
      GLOAD_LDS16(Abase + (size_t)row * K + k0 + slot * 8, &la[chunk * 512]);
      GLOAD_LDS16(Bbase + (size_t)row * K + k0 + slot * 8, &lb[chunk * 512]);
    }
    __syncthreads();
#pragma unroll
    for (int kk = 0; kk < 2; ++kk) {
      bf16x8 af[4], bfr[4];
#pragma unroll
      for (int mi = 0; mi < 4; ++mi) {
        int row = wm + mi * 16 + (lane & 15);
        int slot = (kk * 4 + (lane >> 4)) ^ (row & 7);
        af[mi] = *(const bf16x8*)&la[row * 64 + slot * 8];
      }
#pragma unroll
      for (int ni = 0; ni < 4; ++ni) {
        int row = wn + ni * 16 + (lane & 15);
        int slot = (kk * 4 + (lane >> 4)) ^ (row & 7);
        bfr[ni] = *(const bf16x8*)&lb[row * 64 + slot * 8];
      }
#pragma unroll
      for (int mi = 0; mi < 4; ++mi)
#pragma unroll
        for (int ni = 0; ni < 4; ++ni)
          acc[mi][ni] = __builtin_amdgcn_mfma_f32_16x16x32_bf16(
              af[mi], bfr[ni], acc[mi][ni], 0, 0, 0);
    }
    __syncthreads();
  }

  const int cl = lane & 15;
  const int rl = (lane >> 4) * 4;
#pragma unroll
  for (int mi = 0; mi < 4; ++mi) {
#pragma unroll
    for (int ni = 0; ni < 4; ++ni) {
      int c = bn * 128 + wn + ni * 16 + cl;
      int r0 = bm * 128 + wm + mi * 16 + rl;
      float bs = (MODE == 2) ? bias[c] : 0.f;
#pragma unroll
      for (int j = 0; j < 4; ++j) {
        int r = r0 + j;
        float v = acc[mi][ni][j];
        if (MODE == 2) {
          int b = r & 31, l = r >> 5;
          ((float*)Cptr)[(size_t)(b * L_ + l) * N + c] = v + bs;
        } else {
          ((float*)Cptr)[(size_t)r * N + c] = v;
        }
      }
    }
  }
}

// ------- SRU scan: gates pre-computed by GEMM epilogue (MODE 3) -------------
__global__ void sru_scan_kernel(const float* __restrict__ U,
                                const float* __restrict__ xin, const float* __restrict__ c0,
                                float* __restrict__ hf, short* __restrict__ hb,
                                float* __restrict__ clast) {
  int idx = blockIdx.x * 64 + threadIdx.x;
  int b = idx >> 9, d = idx & 511;
  float c = c0[idx];
  const float* Ub = U + (size_t)b * 1536 + d;
  const float* Xb = xin + (size_t)b * 512 + d;

  for (int l0 = 0; l0 < L_; l0 += 8) {
    float z[8], f[8], r[8], xv[8];
#pragma unroll
    for (int j = 0; j < 8; ++j) {
      size_t u = (size_t)(l0 + j) * B_ * 1536;
      z[j] = Ub[u];
      f[j] = Ub[u + 512];
      r[j] = Ub[u + 1024];
      xv[j] = Xb[(size_t)(l0 + j) * B_ * 512];
    }
#pragma unroll
    for (int j = 0; j < 8; ++j) {
      c = f[j] * c + (1.f - f[j]) * z[j];
      float h = r[j] * tanhf(c) + (1.f - r[j]) * xv[j];
      size_t o = ((size_t)(l0 + j) * B_ + b) * 512 + d;
      hf[o] = h;
      hb[o] = f2bf(h);
    }
  }
  clast[idx] = c;
}

// ---- fused attention v2: one block per (b, l-octet); enc stays L2-local ----
__global__ __launch_bounds__(256) void attn_fused2_kernel(
    const float* __restrict__ x, const float* __restrict__ enc,
    const short* __restrict__ xq, short* __restrict__ cat) {
  __shared__ float q[8][512];
  __shared__ float sc[8][64];
  __shared__ float al[8][64];
  int bid = blockIdx.x;
  int b = bid & 31, lo = bid >> 5;
  int tid = threadIdx.x;
  int wave = tid >> 6, lane = tid & 63;

  // load 8 q rows; copy xq into cat second half
  for (int i = tid; i < 8 * 512; i += 256) {
    int li = i >> 9, d = i & 511;
    size_t r = (size_t)((lo * 8 + li) * B_ + b);
    q[li][d] = x[r * 512 + d];
    cat[r * 1024 + 512 + d] = xq[r * 512 + d];
  }
  __syncthreads();

  // scores: wave w handles s = 16w..16w+15; enc row read once, 8 q-rows reuse
  for (int si = 0; si < 16; ++si) {
    int s = wave * 16 + si;
    const float* m = enc + ((size_t)s * B_ + b) * 512;
    float ev[8];
#pragma unroll
    for (int k = 0; k < 8; ++k) ev[k] = m[lane + 64 * k];
#pragma unroll
    for (int li = 0; li < 8; ++li) {
      float a = 0.f;
#pragma unroll
      for (int k = 0; k < 8; ++k) a += ev[k] * q[li][lane + 64 * k];
      for (int o = 32; o > 0; o >>= 1) a += __shfl_xor(a, o);
      if (lane == 0) sc[li][s] = a;
    }
  }
  __syncthreads();

  // softmax: wave w -> rows 2w, 2w+1; lane indexes s
#pragma unroll
  for (int rr = 0; rr < 2; ++rr) {
    int li = wave * 2 + rr;
    float v = sc[li][lane];
    float mx = v;
    for (int o = 32; o > 0; o >>= 1) mx = fmaxf(mx, __shfl_xor(mx, o));
    float e = expf(v - mx);
    float sm = e;
    for (int o = 32; o > 0; o >>= 1) sm += __shfl_xor(sm, o);
    al[li][lane] = e / sm;
  }
  __syncthreads();

  // ctx: threads over d; enc element read once, 8 rows accumulated
  for (int d = tid; d < 512; d += 256) {
    float acc[8] = {};
    for (int s = 0; s < S_; ++s) {
      float e = enc[((size_t)s * B_ + b) * 512 + d];
#pragma unroll
      for (int li = 0; li < 8; ++li) acc[li] += al[li][s] * e;
    }
#pragma unroll
    for (int li = 0; li < 8; ++li)
      cat[((size_t)((lo * 8 + li) * B_ + b)) * 1024 + d] = f2bf(acc[li]);
  }
}

extern "C" void kernel_launch(void* const* d_in, const int* in_sizes, int n_in,
                              void* d_out, int out_size, void* d_ws, size_t ws_size,
                              hipStream_t stream) {
  const int* rnn = (const int*)d_in[0];
  const float* h0 = (const float*)d_in[1];
  const float* enc = (const float*)d_in[2];
  const float* tab = (const float*)d_in[3];
  const float* sruW = (const float*)d_in[4];
  const float* srub = (const float*)d_in[5];
  const float* attnW = (const float*)d_in[6];
  const float* outW = (const float*)d_in[7];
  const float* outb = (const float*)d_in[8];
  float* out = (float*)d_out;

  char* ws = (char*)d_ws;
  size_t off = 0;
  auto alloc = [&](size_t bytes) {
    char* p = ws + off;
    off += (bytes + 255) & ~(size_t)255;
    return p;
  };
  float* xf = (float*)alloc(4ull * 2048 * 512);
  float* xf2 = (float*)alloc(4ull * 2048 * 512);
  short* xb = (short*)alloc(2ull * 2048 * 512);
  float* U = (float*)alloc(4ull * 2048 * 1536);
  short* WTs = (short*)alloc(2ull * 2 * 1536 * 512);
  short* WTa = (short*)alloc(2ull * 512 * 1024);
  short* WTo = (short*)alloc(2ull * 32000 * 512);
  short* cat = (short*)alloc(2ull * 2048 * 1024);
  short* ah = (short*)alloc(2ull * 2048 * 512);

  prep_kernel<<<22144, dim3(32, 8), 0, stream>>>(sruW, attnW, outW, rnn, tab,
                                                 WTs, WTa, WTo, xf, xb);

  float* hidden_out = out + (size_t)B_ * L_ * V_;

  // layer 0 (U-GEMM fuses gate sigmoids via MODE 3)
  gemm_t<64, 128, 1, 4, 3><<<384, 256, 0, stream>>>(xb, WTs, U, srub, 2048, 1536, 512, 32);
  sru_scan_kernel<<<256, 64, 0, stream>>>(U, xf, h0, xf2, xb, hidden_out);
  // layer 1
  gemm_t<64, 128, 1, 4, 3><<<384, 256, 0, stream>>>(xb, WTs + 1536 * 512, U, srub + 1024,
                                                    2048, 1536, 512, 32);
  sru_scan_kernel<<<256, 64, 0, stream>>>(U, xf2, h0 + B_ * D_, xf, xb,
                                          hidden_out + B_ * D_);

  // fused attention v2: 256 blocks of (b, l-octet)
  attn_fused2_kernel<<<256, 256, 0, stream>>>(xf, enc, xb, cat);

  gemm_t<64, 64, 2, 2, 1><<<256, 256, 0, stream>>>(cat, WTa, ah, nullptr, 2048, 512, 1024, 32);
  // output = attn_h @ out_W + out_b, remapped to [B,L,V]  (m97 single-buffer)
  gemm_s<2><<<4000, 256, 0, stream>>>(ah, WTo, out, outb, 2048, 32000, 512, 16);
}

// Round 9
// 230.365 us; speedup vs baseline: 1.0890x; 1.0890x over previous
//
#include <hip/hip_runtime.h>
#include <hip/hip_bf16.h>

#define L_ 64
#define B_ 32
#define S_ 64
#define D_ 512
#define V_ 32000
#define NL_ 2

typedef __attribute__((ext_vector_type(8))) short bf16x8;
typedef __attribute__((ext_vector_type(4))) float f32x4;

static __device__ __forceinline__ short f2bf(float f) {
  union { float f; unsigned u; } x; x.f = f;
  unsigned r = (x.u + 0x7FFFu + ((x.u >> 16) & 1u)) >> 16;
  return (short)r;
}

#define GLOAD_LDS16(g, l)                                                     \
  __builtin_amdgcn_global_load_lds(                                           \
      (const __attribute__((address_space(1))) void*)(g),                     \
      (__attribute__((address_space(3))) void*)(l), 16, 0, 0)

// ===== fused prep: all weight transposes (f32 [K,N] -> bf16 [N,K]) + embed ==
__global__ void prep_kernel(const float* __restrict__ sruW, const float* __restrict__ attnW,
                            const float* __restrict__ outW, const int* __restrict__ tok,
                            const float* __restrict__ tab,
                            short* __restrict__ WTs, short* __restrict__ WTa,
                            short* __restrict__ WTo,
                            float* __restrict__ xf, short* __restrict__ xb) {
  int bid = blockIdx.x;
  int tx = threadIdx.x, ty = threadIdx.y;  // (32,8)
  __shared__ float tile[32][33];
  if (bid < 18048) {
    const float* in;
    short* out;
    int K, N, bx, by;
    if (bid < 1536) {
      int l = (bid >= 768) ? 1 : 0;
      int r = bid - l * 768;
      bx = r % 48; by = r / 48; K = 512; N = 1536;
      in = sruW + (size_t)l * 512 * 1536;
      out = WTs + (size_t)l * 1536 * 512;
    } else if (bid < 2048) {
      int r = bid - 1536;
      bx = r % 16; by = r / 16; K = 1024; N = 512;
      in = attnW; out = WTa;
    } else {
      int r = bid - 2048;
      bx = r % 1000; by = r / 1000; K = 512; N = 32000;
      in = outW; out = WTo;
    }
    int x = bx * 32 + tx;
    int y0 = by * 32;
    for (int j = ty; j < 32; j += 8) {
      int y = y0 + j;
      tile[j][tx] = (x < N && y < K) ? in[(size_t)y * N + x] : 0.f;
    }
    __syncthreads();
    int xo = y0 + tx;
    int yo0 = bx * 32;
    for (int j = ty; j < 32; j += 8) {
      int yo = yo0 + j;
      if (yo < N && xo < K) out[(size_t)yo * K + xo] = f2bf(tile[tx][j]);
    }
  } else {
    int i = (bid - 18048) * 256 + ty * 32 + tx;
    int d = i & (D_ - 1);
    int lb = i >> 9;
    float v = tab[(size_t)tok[lb] * D_ + d];
    xf[i] = v;
    xb[i] = f2bf(v);
  }
}

// ===== tile-templated 2-phase bf16 MFMA GEMM (small GEMMs; proven) ==========
// MODE 0: f32 C | MODE 1: bf16 tanh(C) | MODE 3: f32, cols>=512 get
// sigmoid(v + bias[c-512]) (SRU gate fusion; bias = srub layer slice)
template <int BMt, int BNt, int WM, int WN, int MODE>
__global__ __launch_bounds__(256) void gemm_t(
    const short* __restrict__ A, const short* __restrict__ BT,
    void* __restrict__ Cptr, const float* __restrict__ bias,
    int M, int N, int K, int nbm) {
  constexpr int MI = BMt / WM / 16;
  constexpr int NI = BNt / WN / 16;
  constexpr int ACH = BMt / 8;
  constexpr int NCH = (BMt + BNt) / 8;
  constexpr int CPW = NCH / 4;

  const int nwg = gridDim.x;
  const int qc = nwg >> 3;
  const int bid = blockIdx.x;
  const int wg = (bid & 7) * qc + (bid >> 3);
  const int bm = wg % nbm;
  const int bn = wg / nbm;

  __shared__ __align__(16) short la[2][BMt * 64];
  __shared__ __align__(16) short lb[2][BNt * 64];
  const int tid = threadIdx.x;
  const int wave = tid >> 6, lane = tid & 63;
  const int wm = (wave / WN) * (BMt / WM);
  const int wn = (wave % WN) * (BNt / WN);

  f32x4 acc[MI][NI] = {};

  const int lrow = lane >> 3;
  const int lslot = lane & 7;
  const short* Abase = A + (size_t)(bm * BMt) * K;
  const short* Bbase = BT + (size_t)(bn * BNt) * K;

  auto stage = [&](int buf, int k0) {
#pragma unroll
    for (int c = 0; c < CPW; ++c) {
      int chunk = wave * CPW + c;
      if (chunk < ACH) {
        int row = chunk * 8 + lrow;
        int slot = lslot ^ (row & 7);
        GLOAD_LDS16(Abase + (size_t)row * K + k0 + slot * 8, &la[buf][chunk * 512]);
      } else {
        int bc = chunk - ACH;
        int row = bc * 8 + lrow;
        int slot = lslot ^ (row & 7);
        GLOAD_LDS16(Bbase + (size_t)row * K + k0 + slot * 8, &lb[buf][bc * 512]);
      }
    }
  };

  stage(0, 0);
  __syncthreads();

  const int nt = K / 64;
  int cur = 0;
  for (int t = 0; t < nt; ++t) {
    if (t + 1 < nt) stage(cur ^ 1, (t + 1) * 64);
#pragma unroll
    for (int kk = 0; kk < 2; ++kk) {
      bf16x8 af[MI], bfr[NI];
#pragma unroll
      for (int mi = 0; mi < MI; ++mi) {
        int row = wm + mi * 16 + (lane & 15);
        int slot = (kk * 4 + (lane >> 4)) ^ (row & 7);
        af[mi] = *(const bf16x8*)&la[cur][row * 64 + slot * 8];
      }
#pragma unroll
      for (int ni = 0; ni < NI; ++ni) {
        int row = wn + ni * 16 + (lane & 15);
        int slot = (kk * 4 + (lane >> 4)) ^ (row & 7);
        bfr[ni] = *(const bf16x8*)&lb[cur][row * 64 + slot * 8];
      }
#pragma unroll
      for (int mi = 0; mi < MI; ++mi)
#pragma unroll
        for (int ni = 0; ni < NI; ++ni)
          acc[mi][ni] = __builtin_amdgcn_mfma_f32_16x16x32_bf16(
              af[mi], bfr[ni], acc[mi][ni], 0, 0, 0);
    }
    __syncthreads();
    cur ^= 1;
  }

  const int cl = lane & 15;
  const int rl = (lane >> 4) * 4;
#pragma unroll
  for (int mi = 0; mi < MI; ++mi) {
#pragma unroll
    for (int ni = 0; ni < NI; ++ni) {
      int c = bn * BNt + wn + ni * 16 + cl;
      int r0 = bm * BMt + wm + mi * 16 + rl;
#pragma unroll
      for (int j = 0; j < 4; ++j) {
        int r = r0 + j;
        float v = acc[mi][ni][j];
        if (MODE == 0) {
          ((float*)Cptr)[(size_t)r * N + c] = v;
        } else if (MODE == 1) {
          ((short*)Cptr)[(size_t)r * N + c] = f2bf(tanhf(v));
        } else if (MODE == 3) {
          if (c >= 512) v = 1.f / (1.f + expf(-(v + bias[c - 512])));
          ((float*)Cptr)[(size_t)r * N + c] = v;
        }
      }
    }
  }
}

// ===== m97-structure single-buffer GEMM (the big V GEMM) ====================
// 32 KB LDS, VGPR~88 -> launch_bounds(256,4) gives 4 blocks/CU (16 waves).
// MODE 2: f32 C[row-remap (l*B+b)->(b*L+l)][N] + bias[n]
template <int MODE>
__global__ __launch_bounds__(256, 4) void gemm_s(
    const short* __restrict__ A, const short* __restrict__ BT,
    void* __restrict__ Cptr, const float* __restrict__ bias,
    int M, int N, int K, int nbm) {
  const int nwg = gridDim.x;
  const int qc = nwg >> 3;
  const int bid = blockIdx.x;
  const int wg = (bid & 7) * qc + (bid >> 3);
  const int bm = wg % nbm;
  const int bn = wg / nbm;

  __shared__ __align__(16) short la[128 * 64];
  __shared__ __align__(16) short lb[128 * 64];
  const int tid = threadIdx.x;
  const int wave = tid >> 6, lane = tid & 63;
  const int wm = (wave >> 1) * 64, wn = (wave & 1) * 64;

  f32x4 acc[4][4] = {};

  const int lrow = lane >> 3;
  const int lslot = lane & 7;
  const short* Abase = A + (size_t)(bm * 128) * K;
  const short* Bbase = BT + (size_t)(bn * 128) * K;

  const int nt = K / 64;
  for (int t = 0; t < nt; ++t) {
    const int k0 = t * 64;
#pragma unroll
    for (int c = 0; c < 4; ++c) {
      int chunk = wave * 4 + c;
      int row = chunk * 8 + lrow;
      int slot = lslot ^ (row & 7);
      GLOAD_LDS16(Abase + (size_t)row * K + k0 + slot * 8, &la[chunk * 512]);
      GLOAD_LDS16(Bbase + (size_t)row * K + k0 + slot * 8, &lb[chunk * 512]);
    }
    __syncthreads();
#pragma unroll
    for (int kk = 0; kk < 2; ++kk) {
      bf16x8 af[4], bfr[4];
#pragma unroll
      for (int mi = 0; mi < 4; ++mi) {
        int row = wm + mi * 16 + (lane & 15);
        int slot = (kk * 4 + (lane >> 4)) ^ (row & 7);
        af[mi] = *(const bf16x8*)&la[row * 64 + slot * 8];
      }
#pragma unroll
      for (int ni = 0; ni < 4; ++ni) {
        int row = wn + ni * 16 + (lane & 15);
        int slot = (kk * 4 + (lane >> 4)) ^ (row & 7);
        bfr[ni] = *(const bf16x8*)&lb[row * 64 + slot * 8];
      }
#pragma unroll
      for (int mi = 0; mi < 4; ++mi)
#pragma unroll
        for (int ni = 0; ni < 4; ++ni)
          acc[mi][ni] = __builtin_amdgcn_mfma_f32_16x16x32_bf16(
              af[mi], bfr[ni], acc[mi][ni], 0, 0, 0);
    }
    __syncthreads();
  }

  const int cl = lane & 15;
  const int rl = (lane >> 4) * 4;
#pragma unroll
  for (int mi = 0; mi < 4; ++mi) {
#pragma unroll
    for (int ni = 0; ni < 4; ++ni) {
      int c = bn * 128 + wn + ni * 16 + cl;
      int r0 = bm * 128 + wm + mi * 16 + rl;
      float bs = (MODE == 2) ? bias[c] : 0.f;
#pragma unroll
      for (int j = 0; j < 4; ++j) {
        int r = r0 + j;
        float v = acc[mi][ni][j];
        if (MODE == 2) {
          int b = r & 31, l = r >> 5;
          ((float*)Cptr)[(size_t)(b * L_ + l) * N + c] = v + bs;
        } else {
          ((float*)Cptr)[(size_t)r * N + c] = v;
        }
      }
    }
  }
}

// ------- SRU scan: gates pre-computed by GEMM epilogue (MODE 3) -------------
__global__ void sru_scan_kernel(const float* __restrict__ U,
                                const float* __restrict__ xin, const float* __restrict__ c0,
                                float* __restrict__ hf, short* __restrict__ hb,
                                float* __restrict__ clast) {
  int idx = blockIdx.x * 64 + threadIdx.x;
  int b = idx >> 9, d = idx & 511;
  float c = c0[idx];
  const float* Ub = U + (size_t)b * 1536 + d;
  const float* Xb = xin + (size_t)b * 512 + d;

  for (int l0 = 0; l0 < L_; l0 += 8) {
    float z[8], f[8], r[8], xv[8];
#pragma unroll
    for (int j = 0; j < 8; ++j) {
      size_t u = (size_t)(l0 + j) * B_ * 1536;
      z[j] = Ub[u];
      f[j] = Ub[u + 512];
      r[j] = Ub[u + 1024];
      xv[j] = Xb[(size_t)(l0 + j) * B_ * 512];
    }
#pragma unroll
    for (int j = 0; j < 8; ++j) {
      c = f[j] * c + (1.f - f[j]) * z[j];
      float h = r[j] * tanhf(c) + (1.f - r[j]) * xv[j];
      size_t o = ((size_t)(l0 + j) * B_ + b) * 512 + d;
      hf[o] = h;
      hb[o] = f2bf(h);
    }
  }
  clast[idx] = c;
}

// ------ fused attention (round-7 proven): per (l,b) row, 2048 blocks --------
__global__ __launch_bounds__(256) void attn_fused_kernel(
    const float* __restrict__ x, const float* __restrict__ enc,
    const short* __restrict__ xq, short* __restrict__ cat) {
  __shared__ float q[512];
  __shared__ float al[64];
  int r = blockIdx.x;
  int b = r & (B_ - 1);
  int tid = threadIdx.x;
  int wave = tid >> 6, lane = tid & 63;
  for (int d = tid; d < 512; d += 256) {
    q[d] = x[(size_t)r * 512 + d];
    cat[(size_t)r * 1024 + 512 + d] = xq[(size_t)r * 512 + d];
  }
  __syncthreads();
#pragma unroll
  for (int si = 0; si < 16; ++si) {
    int s = wave * 16 + si;
    const float* m = enc + ((size_t)s * B_ + b) * 512;
    float a = 0.f;
#pragma unroll
    for (int k = 0; k < 8; ++k) a += q[lane + k * 64] * m[lane + k * 64];
    for (int o = 32; o > 0; o >>= 1) a += __shfl_xor(a, o);
    if (lane == 0) al[s] = a;
  }
  __syncthreads();
  if (tid < 64) {
    float v = al[tid];
    float mx = v;
    for (int o = 32; o > 0; o >>= 1) mx = fmaxf(mx, __shfl_xor(mx, o));
    float e = expf(v - mx);
    float sm = e;
    for (int o = 32; o > 0; o >>= 1) sm += __shfl_xor(sm, o);
    al[tid] = e / sm;
  }
  __syncthreads();
  for (int d = tid; d < 512; d += 256) {
    float acc = 0.f;
#pragma unroll 16
    for (int s = 0; s < S_; ++s) acc += al[s] * enc[((size_t)s * B_ + b) * 512 + d];
    cat[(size_t)r * 1024 + d] = f2bf(acc);
  }
}

extern "C" void kernel_launch(void* const* d_in, const int* in_sizes, int n_in,
                              void* d_out, int out_size, void* d_ws, size_t ws_size,
                              hipStream_t stream) {
  const int* rnn = (const int*)d_in[0];
  const float* h0 = (const float*)d_in[1];
  const float* enc = (const float*)d_in[2];
  const float* tab = (const float*)d_in[3];
  const float* sruW = (const float*)d_in[4];
  const float* srub = (const float*)d_in[5];
  const float* attnW = (const float*)d_in[6];
  const float* outW = (const float*)d_in[7];
  const float* outb = (const float*)d_in[8];
  float* out = (float*)d_out;

  char* ws = (char*)d_ws;
  size_t off = 0;
  auto alloc = [&](size_t bytes) {
    char* p = ws + off;
    off += (bytes + 255) & ~(size_t)255;
    return p;
  };
  float* xf = (float*)alloc(4ull * 2048 * 512);
  float* xf2 = (float*)alloc(4ull * 2048 * 512);
  short* xb = (short*)alloc(2ull * 2048 * 512);
  float* U = (float*)alloc(4ull * 2048 * 1536);
  short* WTs = (short*)alloc(2ull * 2 * 1536 * 512);
  short* WTa = (short*)alloc(2ull * 512 * 1024);
  short* WTo = (short*)alloc(2ull * 32000 * 512);
  short* cat = (short*)alloc(2ull * 2048 * 1024);
  short* ah = (short*)alloc(2ull * 2048 * 512);

  prep_kernel<<<22144, dim3(32, 8), 0, stream>>>(sruW, attnW, outW, rnn, tab,
                                                 WTs, WTa, WTo, xf, xb);

  float* hidden_out = out + (size_t)B_ * L_ * V_;

  // layer 0 (U-GEMM fuses gate sigmoids via MODE 3)
  gemm_t<64, 128, 1, 4, 3><<<384, 256, 0, stream>>>(xb, WTs, U, srub, 2048, 1536, 512, 32);
  sru_scan_kernel<<<256, 64, 0, stream>>>(U, xf, h0, xf2, xb, hidden_out);
  // layer 1
  gemm_t<64, 128, 1, 4, 3><<<384, 256, 0, stream>>>(xb, WTs + 1536 * 512, U, srub + 1024,
                                                    2048, 1536, 512, 32);
  sru_scan_kernel<<<256, 64, 0, stream>>>(U, xf2, h0 + B_ * D_, xf, xb,
                                          hidden_out + B_ * D_);

  // fused attention (2048 blocks, round-7 proven)
  attn_fused_kernel<<<2048, 256, 0, stream>>>(xf, enc, xb, cat);

  gemm_t<64, 64, 2, 2, 1><<<256, 256, 0, stream>>>(cat, WTa, ah, nullptr, 2048, 512, 1024, 32);
  // output = attn_h @ out_W + out_b, remapped to [B,L,V]  (m97 single-buffer)
  gemm_s<2><<<4000, 256, 0, stream>>>(ah, WTo, out, outb, 2048, 32000, 512, 16);
}